// Round 14
// baseline (227.753 us; speedup 1.0000x reference)
//
#include <hip/hip_runtime.h>
#include <cstdint>

#define ALPHA 0.2f

constexpr int NB = 8;
constexpr int NN = 2048;
constexpr int NF = 256;

typedef __attribute__((ext_vector_type(8))) short bf16x8;
typedef __attribute__((ext_vector_type(4))) float f32x4;

__device__ __forceinline__ float bf2f(unsigned short u) {
    union { unsigned int i; float f; } v;
    v.i = ((unsigned int)u) << 16;
    return v.f;
}
__device__ __forceinline__ unsigned short f2bf(float f) {
    union { float f; unsigned int i; } v;
    v.f = f;
    v.i += 0x7fffu + ((v.i >> 16) & 1);  // round-to-nearest-even
    return (unsigned short)(v.i >> 16);
}
// pack two non-negative floats to packed bf16 pair (round-half-up), 3 ops
__device__ __forceinline__ unsigned int pk2bf(float lo, float hi) {
    union { float f; unsigned int u; } a, b;
    a.f = lo; b.f = hi;
    return __builtin_amdgcn_perm(b.u + 0x8000u, a.u + 0x8000u, 0x07060302u);
}

// ---------------------------------------------------------------------------
// Kernel 0: WT[f][k] = bf16(W[k][f]) transpose+cast; also zero s1/s2
// ---------------------------------------------------------------------------
__global__ __launch_bounds__(256) void k_wt(const float* __restrict__ W,
                                            unsigned short* __restrict__ WT,
                                            float* __restrict__ s1,
                                            float* __restrict__ s2) {
    const int t = threadIdx.x;
    const int gid = blockIdx.x * 256 + t;
    s1[gid] = 0.f;
    s2[gid] = 0.f;
    const int k = blockIdx.x * 4 + (t >> 6);
    const int f0 = (t & 63) * 4;
    const float4 w = *(const float4*)&W[k * NF + f0];
    WT[(f0 + 0) * NF + k] = f2bf(w.x);
    WT[(f0 + 1) * NF + k] = f2bf(w.y);
    WT[(f0 + 2) * NF + k] = f2bf(w.z);
    WT[(f0 + 3) * NF + k] = f2bf(w.w);
}

// ---------------------------------------------------------------------------
// Kernel 1: WhT = (h @ W)^T per batch, bf16 MFMA; fused s1/s2 epilogue.
// (unchanged — proven correct, ~6-8 us)
// ---------------------------------------------------------------------------
__global__ __launch_bounds__(256, 4) void k_wh(const float* __restrict__ h,
                                               const unsigned short* __restrict__ WT,
                                               const float* __restrict__ a,
                                               unsigned short* __restrict__ WhT,
                                               float* __restrict__ s1,
                                               float* __restrict__ s2) {
    __shared__ __align__(16) unsigned short As[64][72];  // [row][k] bf16
    __shared__ __align__(16) unsigned short Bs[64][72];  // [f][k]  bf16
    const int tid = threadIdx.x;
    const int lane = tid & 63;
    const int l16 = lane & 15;
    const int quad = lane >> 4;
    const int wave = tid >> 6;

    const int p = blockIdx.x;
    const int xcd = p & 7;
    const int q = p >> 3;                       // 0..127
    const int rowTile = xcd + (q >> 2) * 8;     // 0..255
    const int row0 = rowTile * 64;
    const int col0 = (q & 3) * 64;

    const int bb = row0 >> 11;
    const int n0 = row0 & (NN - 1);
    const int mb = (wave & 1) * 32;
    const int nb = (wave >> 1) * 32;

    f32x4 acc[2][2];
#pragma unroll
    for (int mf = 0; mf < 2; ++mf)
#pragma unroll
        for (int nf = 0; nf < 2; ++nf) acc[mf][nf] = (f32x4){0.f, 0.f, 0.f, 0.f};

    const int r0 = tid >> 4;          // 0..15  (+16 per group)
    const int k4 = (tid & 15) * 4;    // 0..60
    const int f0w = tid >> 3;         // 0..31  (+32 per group)
    const int k8 = (tid & 7) * 8;     // 0..56

    const float* hP = &h[(size_t)(row0 + r0) * NF + k4];
    const unsigned short* wP = &WT[(size_t)(col0 + f0w) * NF + k8];

    float4 h0, h1, h2, h3;
    uint4 wv0, wv1;

#define LOADW(K0)                                                      \
    do {                                                               \
        h0 = *(const float4*)&hP[(size_t)(0 * 16) * NF + (K0)];        \
        h1 = *(const float4*)&hP[(size_t)(1 * 16) * NF + (K0)];        \
        h2 = *(const float4*)&hP[(size_t)(2 * 16) * NF + (K0)];        \
        h3 = *(const float4*)&hP[(size_t)(3 * 16) * NF + (K0)];        \
        wv0 = *(const uint4*)&wP[(K0)];                                \
        wv1 = *(const uint4*)&wP[(size_t)32 * NF + (K0)];              \
    } while (0)

    LOADW(0);

    for (int k0 = 0; k0 < NF; k0 += 64) {
        ushort4 o;
        o.x = f2bf(h0.x); o.y = f2bf(h0.y); o.z = f2bf(h0.z); o.w = f2bf(h0.w);
        *(ushort4*)&As[r0 + 0][k4] = o;
        o.x = f2bf(h1.x); o.y = f2bf(h1.y); o.z = f2bf(h1.z); o.w = f2bf(h1.w);
        *(ushort4*)&As[r0 + 16][k4] = o;
        o.x = f2bf(h2.x); o.y = f2bf(h2.y); o.z = f2bf(h2.z); o.w = f2bf(h2.w);
        *(ushort4*)&As[r0 + 32][k4] = o;
        o.x = f2bf(h3.x); o.y = f2bf(h3.y); o.z = f2bf(h3.z); o.w = f2bf(h3.w);
        *(ushort4*)&As[r0 + 48][k4] = o;
        *(uint4*)&Bs[f0w][k8] = wv0;
        *(uint4*)&Bs[f0w + 32][k8] = wv1;
        __syncthreads();
        if (k0 + 64 < NF) LOADW(k0 + 64);
#pragma unroll
        for (int ks = 0; ks < 64; ks += 32) {
            bf16x8 av[2], bv[2];
#pragma unroll
            for (int mf = 0; mf < 2; ++mf)
                av[mf] = *(const bf16x8*)&As[mb + mf * 16 + l16][ks + quad * 8];
#pragma unroll
            for (int nf = 0; nf < 2; ++nf)
                bv[nf] = *(const bf16x8*)&Bs[nb + nf * 16 + l16][ks + quad * 8];
#pragma unroll
            for (int mf = 0; mf < 2; ++mf)
#pragma unroll
                for (int nf = 0; nf < 2; ++nf)
                    acc[mf][nf] = __builtin_amdgcn_mfma_f32_16x16x32_bf16(
                        av[mf], bv[nf], acc[mf][nf], 0, 0, 0);
        }
        __syncthreads();
    }
#undef LOADW

#pragma unroll
    for (int mf = 0; mf < 2; ++mf) {
#pragma unroll
        for (int nf = 0; nf < 2; ++nf) {
            const size_t f = col0 + nb + nf * 16 + l16;
            const int nr = n0 + mb + mf * 16 + quad * 4;
            ushort4 o;
            o.x = f2bf(acc[mf][nf][0]);
            o.y = f2bf(acc[mf][nf][1]);
            o.z = f2bf(acc[mf][nf][2]);
            o.w = f2bf(acc[mf][nf][3]);
            *(ushort4*)&WhT[((size_t)bb * NF + f) * NN + nr] = o;
        }
    }

    float a1v[2], a2v[2];
#pragma unroll
    for (int nf = 0; nf < 2; ++nf) {
        const int f = col0 + nb + nf * 16 + l16;
        a1v[nf] = a[f];
        a2v[nf] = a[NF + f];
    }
#pragma unroll
    for (int mf = 0; mf < 2; ++mf) {
#pragma unroll
        for (int r = 0; r < 4; ++r) {
            float p1 = acc[mf][0][r] * a1v[0] + acc[mf][1][r] * a1v[1];
            float p2 = acc[mf][0][r] * a2v[0] + acc[mf][1][r] * a2v[1];
            p1 += __shfl_xor(p1, 1); p2 += __shfl_xor(p2, 1);
            p1 += __shfl_xor(p1, 2); p2 += __shfl_xor(p2, 2);
            p1 += __shfl_xor(p1, 4); p2 += __shfl_xor(p2, 4);
            p1 += __shfl_xor(p1, 8); p2 += __shfl_xor(p2, 8);
            if (l16 == 0) {
                const int n = n0 + mb + mf * 16 + quad * 4 + r;
                atomicAdd(&s1[bb * NN + n], p1);
                atomicAdd(&s2[bb * NN + n], p2);
            }
        }
    }
}

// ---------------------------------------------------------------------------
// Kernel 2: fused masked softmax + attn @ Wh.
// = r13 (best measured, ~65us: QBLK=32, JBLK=128, WhsT staging,
// prefetch-1-ahead, register row-sums, grid 512, batch/XCD) with ONE
// change: bar2 (post-MFMA, pure LDS-WAR) is a raw s_barrier with
// lgkmcnt(0)-only drain — NO vmcnt(0). The LOAD_TILE(t+1) prefetch
// issued before the MFMA phase now stays in flight across bar2; each
// wave waits for it independently at the first w-register use after
// the barrier instead of all waves gating on a collective drain.
// Safety: a wave's Pb/WhsT ds_reads are complete before it reaches
// bar2 (their results feed MFMAs issued before the barrier; explicit
// lgkmcnt(0) + sched_barrier(0) fences prevent compiler sinking —
// rule-18 guard). bar1 keeps full __syncthreads (nothing in flight).
// ---------------------------------------------------------------------------
__global__ __launch_bounds__(256, 2) void k_attn(const unsigned short* __restrict__ WhT,
                                                 const int* __restrict__ adj,
                                                 const float* __restrict__ s1g,
                                                 const float* __restrict__ s2g,
                                                 float* __restrict__ out) {
    __shared__ __align__(16) unsigned short WhsT[256][136];  // [f][j] 69.6 KB
    __shared__ __align__(16) unsigned short Pb[32][136];     // [i][j] 8.7 KB
    __shared__ float l_s[32];

    const int tid = threadIdx.x;
    const int lane = tid & 63;
    const int l16 = lane & 15;
    const int quad = lane >> 4;
    const int wave = tid >> 6;
    const int bb = blockIdx.x & 7;           // one batch per XCD
    const int i0 = (blockIdx.x >> 3) * 32;   // q-tile base

    f32x4 acc[2][4];
#pragma unroll
    for (int m = 0; m < 2; ++m)
#pragma unroll
        for (int nf = 0; nf < 4; ++nf) acc[m][nf] = (f32x4){0.f, 0.f, 0.f, 0.f};

    const size_t whtBase = (size_t)bb * NF * NN;
    const size_t adjBase = (size_t)bb * NN * NN;

    // staging geometry: 16 uint4/thread cover WhsT[256][128]
    const int whF = tid >> 4;            // 0..15 (+16 per round, 16 rounds)
    const int whKj = (tid & 15) * 8;     // j-offset 0..120
    // P geometry: thread covers rows {pIr, pIr+16}, 8 j's at pKq..pKq+7
    const int pIr = tid >> 4;            // 0..15
    const int pKq = (tid & 15) * 8;      // 0..120

    const unsigned short* whP = &WhT[whtBase + (size_t)whF * NN + whKj];
    const int* adjP0 = &adj[adjBase + (size_t)(i0 + pIr) * NN + pKq];
    const int* adjP1 = adjP0 + 16 * NN;
    const float* s2P = &s2g[bb * NN + pKq];

    // loop-invariant s1 in registers; register row-sum accumulators
    const float s1v0 = s1g[bb * NN + i0 + pIr];
    const float s1v1 = s1g[bb * NN + i0 + pIr + 16];
    float lsum0 = 0.f, lsum1 = 0.f;

    // named prefetch registers (one full 128-j tile ahead)
    uint4 w0, w1, w2, w3, w4, w5, w6, w7, w8, w9, wa, wb, wc, wd, we, wf;
    int4 am0a, am0b, am1a, am1b;
    float4 sva, svb;

#define LOAD_TILE(J0)                                                         \
    do {                                                                      \
        const int j0_ = (J0);                                                 \
        w0 = *(const uint4*)&whP[(size_t)(0 * 16) * NN + j0_];                \
        w1 = *(const uint4*)&whP[(size_t)(1 * 16) * NN + j0_];                \
        w2 = *(const uint4*)&whP[(size_t)(2 * 16) * NN + j0_];                \
        w3 = *(const uint4*)&whP[(size_t)(3 * 16) * NN + j0_];                \
        w4 = *(const uint4*)&whP[(size_t)(4 * 16) * NN + j0_];                \
        w5 = *(const uint4*)&whP[(size_t)(5 * 16) * NN + j0_];                \
        w6 = *(const uint4*)&whP[(size_t)(6 * 16) * NN + j0_];                \
        w7 = *(const uint4*)&whP[(size_t)(7 * 16) * NN + j0_];                \
        w8 = *(const uint4*)&whP[(size_t)(8 * 16) * NN + j0_];                \
        w9 = *(const uint4*)&whP[(size_t)(9 * 16) * NN + j0_];                \
        wa = *(const uint4*)&whP[(size_t)(10 * 16) * NN + j0_];               \
        wb = *(const uint4*)&whP[(size_t)(11 * 16) * NN + j0_];               \
        wc = *(const uint4*)&whP[(size_t)(12 * 16) * NN + j0_];               \
        wd = *(const uint4*)&whP[(size_t)(13 * 16) * NN + j0_];               \
        we = *(const uint4*)&whP[(size_t)(14 * 16) * NN + j0_];               \
        wf = *(const uint4*)&whP[(size_t)(15 * 16) * NN + j0_];               \
        am0a = *(const int4*)&adjP0[j0_];                                     \
        am0b = *(const int4*)&adjP0[j0_ + 4];                                 \
        am1a = *(const int4*)&adjP1[j0_];                                     \
        am1b = *(const int4*)&adjP1[j0_ + 4];                                 \
        sva = *(const float4*)&s2P[j0_];                                      \
        svb = *(const float4*)&s2P[j0_ + 4];                                  \
    } while (0)

    // P for one row: 8 j's -> one uint4 Pb write + running sum
#define PROW(S1V, AMA, AMB, ROW, LSUM)                                        \
    do {                                                                      \
        float x0 = (S1V) + sva.x, x1 = (S1V) + sva.y;                         \
        float x2 = (S1V) + sva.z, x3 = (S1V) + sva.w;                         \
        float x4 = (S1V) + svb.x, x5 = (S1V) + svb.y;                         \
        float x6 = (S1V) + svb.z, x7 = (S1V) + svb.w;                         \
        x0 = fmaxf(x0, ALPHA * x0);                                           \
        x1 = fmaxf(x1, ALPHA * x1);                                           \
        x2 = fmaxf(x2, ALPHA * x2);                                           \
        x3 = fmaxf(x3, ALPHA * x3);                                           \
        x4 = fmaxf(x4, ALPHA * x4);                                           \
        x5 = fmaxf(x5, ALPHA * x5);                                           \
        x6 = fmaxf(x6, ALPHA * x6);                                           \
        x7 = fmaxf(x7, ALPHA * x7);                                           \
        const float p0 = AMA.x > 0 ? __expf(x0) : 0.f;                        \
        const float p1 = AMA.y > 0 ? __expf(x1) : 0.f;                        \
        const float p2 = AMA.z > 0 ? __expf(x2) : 0.f;                        \
        const float p3 = AMA.w > 0 ? __expf(x3) : 0.f;                        \
        const float p4 = AMB.x > 0 ? __expf(x4) : 0.f;                        \
        const float p5 = AMB.y > 0 ? __expf(x5) : 0.f;                        \
        const float p6 = AMB.z > 0 ? __expf(x6) : 0.f;                        \
        const float p7 = AMB.w > 0 ? __expf(x7) : 0.f;                        \
        uint4 pk;                                                             \
        pk.x = pk2bf(p0, p1);                                                 \
        pk.y = pk2bf(p2, p3);                                                 \
        pk.z = pk2bf(p4, p5);                                                 \
        pk.w = pk2bf(p6, p7);                                                 \
        *(uint4*)&Pb[ROW][pKq] = pk;                                          \
        LSUM += ((p0 + p1) + (p2 + p3)) + ((p4 + p5) + (p6 + p7));            \
    } while (0)

    LOAD_TILE(0);

    for (int t = 0; t < NN / 128; ++t) {
        // ---- prefetched WhT -> LDS (16 rounds of 16 rows) ----
        *(uint4*)&WhsT[whF + 0 * 16][whKj] = w0;
        *(uint4*)&WhsT[whF + 1 * 16][whKj] = w1;
        *(uint4*)&WhsT[whF + 2 * 16][whKj] = w2;
        *(uint4*)&WhsT[whF + 3 * 16][whKj] = w3;
        *(uint4*)&WhsT[whF + 4 * 16][whKj] = w4;
        *(uint4*)&WhsT[whF + 5 * 16][whKj] = w5;
        *(uint4*)&WhsT[whF + 6 * 16][whKj] = w6;
        *(uint4*)&WhsT[whF + 7 * 16][whKj] = w7;
        *(uint4*)&WhsT[whF + 8 * 16][whKj] = w8;
        *(uint4*)&WhsT[whF + 9 * 16][whKj] = w9;
        *(uint4*)&WhsT[whF + 10 * 16][whKj] = wa;
        *(uint4*)&WhsT[whF + 11 * 16][whKj] = wb;
        *(uint4*)&WhsT[whF + 12 * 16][whKj] = wc;
        *(uint4*)&WhsT[whF + 13 * 16][whKj] = wd;
        *(uint4*)&WhsT[whF + 14 * 16][whKj] = we;
        *(uint4*)&WhsT[whF + 15 * 16][whKj] = wf;
        // ---- P: rows pIr and pIr+16, 8 j's each ----
        PROW(s1v0, am0a, am0b, pIr, lsum0);
        PROW(s1v1, am1a, am1b, pIr + 16, lsum1);
        __syncthreads();  // bar1: publish Pb/WhsT (vmcnt empty here — free)
        // ---- issue next tile's loads (fly during MFMA AND across bar2) ----
        if (t + 1 < NN / 128) LOAD_TILE((t + 1) * 128);
        // ---- MFMA: out[32 x 64f per wave] += P[32 x 128j] * WhsT^T ----
        const int f0 = wave * 64;
#pragma unroll
        for (int k0 = 0; k0 < 128; k0 += 32) {
            bf16x8 af[2];
#pragma unroll
            for (int m = 0; m < 2; ++m)
                af[m] = *(const bf16x8*)&Pb[m * 16 + l16][k0 + quad * 8];
#pragma unroll
            for (int nf = 0; nf < 4; ++nf) {
                const bf16x8 bfr =
                    *(const bf16x8*)&WhsT[f0 + nf * 16 + l16][k0 + quad * 8];
#pragma unroll
                for (int m = 0; m < 2; ++m)
                    acc[m][nf] = __builtin_amdgcn_mfma_f32_16x16x32_bf16(
                        af[m], bfr, acc[m][nf], 0, 0, 0);
            }
        }
        // ---- bar2: LDS-WAR only. lgkmcnt(0) (reads already done — feeds
        // MFMA) + raw s_barrier. NO vmcnt drain: prefetch stays in flight.
        // sched_barrier fences stop the compiler sinking ds_reads/MFMAs
        // below the barrier (rule-18 guard).
        __builtin_amdgcn_sched_barrier(0);
        asm volatile("s_waitcnt lgkmcnt(0)" ::: "memory");
        __builtin_amdgcn_sched_barrier(0);
        __builtin_amdgcn_s_barrier();
        __builtin_amdgcn_sched_barrier(0);
    }
#undef LOAD_TILE
#undef PROW

    // ---- one-time row-sum reduce (16 threads per row, consecutive lanes) ----
    lsum0 += __shfl_xor(lsum0, 1);
    lsum0 += __shfl_xor(lsum0, 2);
    lsum0 += __shfl_xor(lsum0, 4);
    lsum0 += __shfl_xor(lsum0, 8);
    lsum1 += __shfl_xor(lsum1, 1);
    lsum1 += __shfl_xor(lsum1, 2);
    lsum1 += __shfl_xor(lsum1, 4);
    lsum1 += __shfl_xor(lsum1, 8);
    if ((tid & 15) == 0) {
        l_s[pIr] = 1.0f / lsum0;
        l_s[pIr + 16] = 1.0f / lsum1;
    }
    __syncthreads();

    // ---- epilogue ----
    const int f0 = wave * 64;
#pragma unroll
    for (int m = 0; m < 2; ++m) {
#pragma unroll
        for (int r = 0; r < 4; ++r) {
            const int row = m * 16 + quad * 4 + r;
            const float inv = l_s[row];
#pragma unroll
            for (int nf = 0; nf < 4; ++nf) {
                out[((size_t)bb * NN + i0 + row) * NF + f0 + nf * 16 + l16] =
                    acc[m][nf][r] * inv;
            }
        }
    }
}

// ---------------------------------------------------------------------------
extern "C" void kernel_launch(void* const* d_in, const int* in_sizes, int n_in,
                              void* d_out, int out_size, void* d_ws, size_t ws_size,
                              hipStream_t stream) {
    const float* h = (const float*)d_in[0];
    const int* adj = (const int*)d_in[1];
    const float* W = (const float*)d_in[2];
    const float* a = (const float*)d_in[3];
    float* out = (float*)d_out;

    unsigned short* WhT = (unsigned short*)d_ws;  // 8.4 MB bf16, [b][f][n]
    float* s1 = (float*)((char*)d_ws + (size_t)NB * NN * NF * sizeof(unsigned short));
    float* s2 = s1 + (size_t)NB * NN;
    unsigned short* WT = (unsigned short*)(s2 + (size_t)NB * NN);  // 128 KB

    k_wt<<<dim3(64), dim3(256), 0, stream>>>(W, WT, s1, s2);
    k_wh<<<dim3((NB * NN / 64) * (NF / 64)), dim3(256), 0, stream>>>(h, WT, a, WhT, s1, s2);
    // grid = NB batches x (NN/32) q-tiles = 512 blocks (one batch per XCD)
    k_attn<<<dim3(NB * (NN / 32)), dim3(256), 0, stream>>>(WhT, adj, s1, s2, out);
}